// Round 12
// baseline (581.293 us; speedup 1.0000x reference)
//
#include <hip/hip_runtime.h>
#include <math.h>

#define N_NODES 50000
#define N_EDGES 800000
#define N_QE    100000
#define D       128

typedef _Float16 f16;
typedef f16 half8 __attribute__((ext_vector_type(8)));
typedef float f32x4 __attribute__((ext_vector_type(4)));

// ---- workspace layout (bytes) ----
static const size_t O_CNT = 0;                        // int[N]
static const size_t O_OFF = 256u * 1024;              // int[N+1]
static const size_t O_CUR = 512u * 1024;              // int[N]
static const size_t O_BS  = 768u * 1024;              // int[256] block sums
static const size_t O_SRC = 1024u * 1024;             // int[E] (3.2 MB)
static const size_t O_A   = 8u << 20;                 // float[N*D] 25.6 MB
static const size_t O_B   = O_A + 25600000u;          // float[N*D] 25.6 MB
static const size_t O_WT  = O_B + 25600000u;          // f16 4x[128][128] = 128 KB

// ---- CSR build ----
__global__ void k_count(const int* __restrict__ dst, int* __restrict__ cnt) {
    int e = blockIdx.x * 256 + threadIdx.x;
    if (e < N_EDGES) atomicAdd(&cnt[dst[e]], 1);
}

__global__ __launch_bounds__(256)
void k_scan1(const int* __restrict__ cnt, int* __restrict__ off,
             int* __restrict__ bsum) {
    __shared__ int sh[256];
    const int t = threadIdx.x;
    const int i = blockIdx.x * 256 + t;
    int v = (i < N_NODES) ? cnt[i] : 0;
    sh[t] = v;
    __syncthreads();
    #pragma unroll
    for (int o = 1; o < 256; o <<= 1) {
        int u = (t >= o) ? sh[t - o] : 0;
        __syncthreads();
        sh[t] += u;
        __syncthreads();
    }
    if (i < N_NODES) off[i] = sh[t] - v;
    if (t == 255) bsum[blockIdx.x] = sh[255];
}

__global__ __launch_bounds__(256)
void k_scan2(int* __restrict__ bsum, int nblk) {
    __shared__ int sh[256];
    const int t = threadIdx.x;
    int v = (t < nblk) ? bsum[t] : 0;
    sh[t] = v;
    __syncthreads();
    #pragma unroll
    for (int o = 1; o < 256; o <<= 1) {
        int u = (t >= o) ? sh[t - o] : 0;
        __syncthreads();
        sh[t] += u;
        __syncthreads();
    }
    if (t < nblk) bsum[t] = sh[t] - v;
}

__global__ __launch_bounds__(256)
void k_scan3(int* __restrict__ off, const int* __restrict__ bsum,
             int* __restrict__ cur) {
    const int i = blockIdx.x * 256 + threadIdx.x;
    if (i < N_NODES) {
        int o = off[i] + bsum[blockIdx.x];
        off[i] = o;
        cur[i] = o;
    }
    if (i == 0) off[N_NODES] = N_EDGES;
}

__global__ void k_scatter(const int* __restrict__ src, const int* __restrict__ dst,
                          int* __restrict__ cur, int* __restrict__ srcs) {
    int e = blockIdx.x * 256 + threadIdx.x;
    if (e < N_EDGES) {
        int p = atomicAdd(&cur[dst[e]], 1);
        srcs[p] = src[e];
    }
}

// ---- W-prep: P1,P2 -> transposed fp16 hi/lo arrays [n][k] ----
__global__ __launch_bounds__(256)
void k_wprep(const float* __restrict__ P1, const float* __restrict__ P2,
             f16* __restrict__ wt) {
    int t = blockIdx.x * 256 + threadIdx.x;     // 0..32767
    int w = t >> 14, idx = t & 16383;
    int k = idx >> 7, n = idx & 127;
    float v = (w ? P2 : P1)[idx];
    f16 h = (f16)v;
    f16 l = (f16)(v - (float)h);
    f16* base = wt + (size_t)w * 32768;
    base[(size_t)n * 128 + k] = h;
    base[16384 + (size_t)n * 128 + k] = l;
}

// ---- GEMM: Y[rows x 128] = X[rows x 128] @ W[128 x 128], fp32 ----
__global__ __launch_bounds__(512)
void k_gemm(const float* __restrict__ X, const float* __restrict__ W,
            float* __restrict__ Y, int rows)
{
    __shared__ float xs[64][36];
    __shared__ float ws[32 * 128];
    const int tid = threadIdx.x;
    const int tx = tid & 31;
    const int ty = tid >> 5;
    const int row0 = blockIdx.x * 64;
    float acc[4][4] = {};

    for (int kc = 0; kc < 4; ++kc) {
        const int kb = kc * 32;
        __syncthreads();
        {
            int r = tid >> 3, kq = tid & 7;
            int gr = row0 + r; if (gr >= rows) gr = rows - 1;
            float4 v = *(const float4*)(X + (size_t)gr * D + kb + kq * 4);
            *(float4*)&xs[r][kq * 4] = v;
        }
        #pragma unroll
        for (int it = 0; it < 2; ++it) {
            int f = it * 512 + tid;
            int k = f >> 5, cq = f & 31;
            *(float4*)&ws[k * 128 + cq * 4] =
                *(const float4*)(W + (size_t)(kb + k) * D + cq * 4);
        }
        __syncthreads();

        #pragma unroll 2
        for (int k4 = 0; k4 < 32; k4 += 4) {
            float4 wv[4];
            #pragma unroll
            for (int kk = 0; kk < 4; ++kk)
                wv[kk] = *(const float4*)&ws[(k4 + kk) * 128 + tx * 4];
            #pragma unroll
            for (int i = 0; i < 4; ++i) {
                float4 xv = *(const float4*)&xs[ty * 4 + i][k4];
                float xk[4] = {xv.x, xv.y, xv.z, xv.w};
                #pragma unroll
                for (int kk = 0; kk < 4; ++kk) {
                    acc[i][0] = fmaf(xk[kk], wv[kk].x, acc[i][0]);
                    acc[i][1] = fmaf(xk[kk], wv[kk].y, acc[i][1]);
                    acc[i][2] = fmaf(xk[kk], wv[kk].z, acc[i][2]);
                    acc[i][3] = fmaf(xk[kk], wv[kk].w, acc[i][3]);
                }
            }
        }
    }

    #pragma unroll
    for (int i = 0; i < 4; ++i) {
        int gr = row0 + ty * 4 + i;
        if (gr < rows)
            *(float4*)(Y + (size_t)gr * D + tx * 4) =
                make_float4(acc[i][0], acc[i][1], acc[i][2], acc[i][3]);
    }
}

// ---- CSR aggregation (fp32): 2 waves per node, 2 nodes per block ----
template<bool RELU>
__global__ __launch_bounds__(256)
void k_agg(const float* __restrict__ Hin, const int* __restrict__ off,
           const int* __restrict__ srcs, const float* __restrict__ bias,
           float* __restrict__ Hout)
{
    __shared__ float4 red[4][32];
    const int tid  = threadIdx.x;
    const int lane = tid & 63;
    const int wid  = tid >> 6;
    const int slot = wid >> 1;
    const int sub  = wid & 1;
    const int n    = blockIdx.x * 2 + slot;
    const int half = lane >> 5;
    const int q    = lane & 31;
    const int j0 = off[n], j1 = off[n + 1];
    const int mid = j0 + ((j1 - j0 + 1) >> 1);
    const int jb = sub ? mid : j0;
    const int je = sub ? j1 : mid;

    float4 acc = make_float4(0.f, 0.f, 0.f, 0.f);
    int j = jb;
    while (j < je) {
        int cnt = je - j; if (cnt > 64) cnt = 64;
        int idx = (lane < cnt) ? srcs[j + lane] : 0;
        #pragma unroll 8
        for (int k = half; k < cnt; k += 2) {
            int s = __shfl(idx, k, 64);
            const float4 v = *(const float4*)(Hin + (size_t)s * D + q * 4);
            acc.x += v.x; acc.y += v.y; acc.z += v.z; acc.w += v.w;
        }
        j += cnt;
    }
    acc.x += __shfl_xor(acc.x, 32, 64);
    acc.y += __shfl_xor(acc.y, 32, 64);
    acc.z += __shfl_xor(acc.z, 32, 64);
    acc.w += __shfl_xor(acc.w, 32, 64);
    if (half == 0) red[wid][q] = acc;
    __syncthreads();
    if (sub == 0 && half == 0) {
        float4 a = red[wid][q];
        float4 b = red[wid + 1][q];
        const float4 bb = *(const float4*)(bias + q * 4);
        float4 o = make_float4(a.x + b.x + bb.x, a.y + b.y + bb.y,
                               a.z + b.z + bb.z, a.w + b.w + bb.w);
        if (RELU) {
            o.x = fmaxf(o.x, 0.f); o.y = fmaxf(o.y, 0.f);
            o.z = fmaxf(o.z, 0.f); o.w = fmaxf(o.w, 0.f);
        }
        *(float4*)(Hout + (size_t)n * D + q * 4) = o;
    }
}

// ---- fused link predictor: MFMA fp16x2-split v2 ----
// 8 waves x 16 edges. Layer-1 A-frags computed DIRECTLY from the emb gather
// (lane(quad,l15) owns exactly A[m=l15][k=kt*32+quad*8..+7] = z0 elements;
// no LDS staging, no bank conflicts). Layer1->2 handoff via one f32 LDS
// buffer [128][132] (stride 132 dw -> worst 2-way = free), split on read.
// Per nt: preload all 8 B-frags (needs VGPRs: launch_bounds(512,2) caps 256),
// then 3 independent 4-deep MFMA chains (ah*bl, al*bh, ah*bh).
__global__ __launch_bounds__(512, 2)
void k_pred(const float* __restrict__ emb, const int* __restrict__ te,
            const f16* __restrict__ wt,
            const float* __restrict__ pb1, const float* __restrict__ pb2,
            const float* __restrict__ P3, const float* __restrict__ pb3,
            float* __restrict__ out)
{
    __shared__ float h1[128][132];    // 67.6 KB
    const int tid  = threadIdx.x;
    const int lane = tid & 63;
    const int w    = tid >> 6;        // wave 0..7
    const int quad = lane >> 4;
    const int l15  = lane & 15;
    const int row0 = blockIdx.x * 128 + w * 16;

    const float SC = 0.015625f;       // 1/64 pre-scale (fp16 overflow guard)

    half8 ah[4], al[4];
    // layer-1 A-frags direct from emb
    {
        int e = row0 + l15; if (e >= N_QE) e = N_QE - 1;
        int2 ep = *(const int2*)(te + 2 * e);
        const float* ps = emb + (size_t)ep.x * D;
        const float* pd = emb + (size_t)ep.y * D;
        #pragma unroll
        for (int kt = 0; kt < 4; ++kt) {
            int c0 = kt * 32 + quad * 8;
            float4 s0 = *(const float4*)(ps + c0);
            float4 s1 = *(const float4*)(ps + c0 + 4);
            float4 d0 = *(const float4*)(pd + c0);
            float4 d1 = *(const float4*)(pd + c0 + 4);
            float v[8] = {s0.x * d0.x * SC, s0.y * d0.y * SC,
                          s0.z * d0.z * SC, s0.w * d0.w * SC,
                          s1.x * d1.x * SC, s1.y * d1.y * SC,
                          s1.z * d1.z * SC, s1.w * d1.w * SC};
            #pragma unroll
            for (int m = 0; m < 8; ++m) {
                f16 h = (f16)v[m];
                ah[kt][m] = h;
                al[kt][m] = (f16)(v[m] - (float)h);
            }
        }
    }

    f32x4 acc[8];
    #pragma unroll
    for (int layer = 0; layer < 2; ++layer) {
        const f16* Wh = wt + (size_t)layer * 32768;
        const f16* Wl = Wh + 16384;
        const float* bb = layer ? pb2 : pb1;
        const float unsc = layer ? 1.f : 64.f;

        if (layer == 1) {
            // reload A-frags from h1 (own rows), split on the fly
            const float* hp = &h1[w * 16 + l15][0];
            #pragma unroll
            for (int kt = 0; kt < 4; ++kt) {
                int c0 = kt * 32 + quad * 8;
                float4 u0 = *(const float4*)(hp + c0);
                float4 u1 = *(const float4*)(hp + c0 + 4);
                float v[8] = {u0.x, u0.y, u0.z, u0.w, u1.x, u1.y, u1.z, u1.w};
                #pragma unroll
                for (int m = 0; m < 8; ++m) {
                    f16 h = (f16)v[m];
                    ah[kt][m] = h;
                    al[kt][m] = (f16)(v[m] - (float)h);
                }
            }
        }

        #pragma unroll
        for (int nt = 0; nt < 8; ++nt) {
            const int n = nt * 16 + l15;
            const size_t b0 = (size_t)n * 128 + quad * 8;
            half8 bh[4], bl[4];
            #pragma unroll
            for (int kt = 0; kt < 4; ++kt) {
                bh[kt] = *(const half8*)(Wh + b0 + kt * 32);
                bl[kt] = *(const half8*)(Wl + b0 + kt * 32);
            }
            f32x4 chh = {0.f, 0.f, 0.f, 0.f};
            f32x4 chl = {0.f, 0.f, 0.f, 0.f};
            f32x4 clh = {0.f, 0.f, 0.f, 0.f};
            #pragma unroll
            for (int kt = 0; kt < 4; ++kt) {
                chl = __builtin_amdgcn_mfma_f32_16x16x32_f16(ah[kt], bl[kt], chl, 0, 0, 0);
                clh = __builtin_amdgcn_mfma_f32_16x16x32_f16(al[kt], bh[kt], clh, 0, 0, 0);
                chh = __builtin_amdgcn_mfma_f32_16x16x32_f16(ah[kt], bh[kt], chh, 0, 0, 0);
            }
            acc[nt] = (chh + chl) + clh;
        }

        // bias + relu (+ unscale for layer 0)
        #pragma unroll
        for (int nt = 0; nt < 8; ++nt) {
            float b = bb[nt * 16 + l15];
            #pragma unroll
            for (int r = 0; r < 4; ++r)
                acc[nt][r] = fmaxf(acc[nt][r] * unsc + b, 0.f);
        }
        if (layer == 0) {
            // write h1 in C layout (m=quad*4+r, n=nt*16+l15)
            #pragma unroll
            for (int nt = 0; nt < 8; ++nt)
                #pragma unroll
                for (int r = 0; r < 4; ++r)
                    h1[w * 16 + quad * 4 + r][nt * 16 + l15] = acc[nt][r];
            __syncthreads();
        }
    }

    // epilogue: v = h2 @ P3 + pb3 (2 cols); reduce across the 16 l15 lanes
    float p0[4] = {0.f, 0.f, 0.f, 0.f}, p1[4] = {0.f, 0.f, 0.f, 0.f};
    #pragma unroll
    for (int nt = 0; nt < 8; ++nt) {
        float2 p3 = *(const float2*)(P3 + (size_t)(nt * 16 + l15) * 2);
        #pragma unroll
        for (int r = 0; r < 4; ++r) {
            p0[r] += acc[nt][r] * p3.x;
            p1[r] += acc[nt][r] * p3.y;
        }
    }
    #pragma unroll
    for (int r = 0; r < 4; ++r) {
        #pragma unroll
        for (int o = 1; o < 16; o <<= 1) {
            p0[r] += __shfl_xor(p0[r], o, 64);
            p1[r] += __shfl_xor(p1[r], o, 64);
        }
    }
    if (l15 == 0) {
        const float q0 = pb3[0], q1 = pb3[1];
        #pragma unroll
        for (int r = 0; r < 4; ++r) {
            int gr = row0 + quad * 4 + r;
            if (gr < N_QE) {
                float v0 = p0[r] + q0, v1 = p1[r] + q1;
                float nrm = fmaxf(sqrtf(v0 * v0 + v1 * v1), 1e-12f);
                v0 /= nrm; v1 /= nrm;
                float m = fmaxf(v0, v1);
                float lse = m + logf(expf(v0 - m) + expf(v1 - m));
                out[gr * 2]     = v0 - lse;
                out[gr * 2 + 1] = v1 - lse;
            }
        }
    }
}

extern "C" void kernel_launch(void* const* d_in, const int* in_sizes, int n_in,
                              void* d_out, int out_size, void* d_ws, size_t ws_size,
                              hipStream_t stream)
{
    (void)in_sizes; (void)n_in; (void)out_size; (void)ws_size;
    const float* x   = (const float*)d_in[0];
    const int*   adj = (const int*)d_in[1];
    const int*   te  = (const int*)d_in[2];
    const float* W1  = (const float*)d_in[3];
    const float* b1  = (const float*)d_in[4];
    const float* W2  = (const float*)d_in[5];
    const float* b2  = (const float*)d_in[6];
    const float* W3  = (const float*)d_in[7];
    const float* b3  = (const float*)d_in[8];
    const float* P1  = (const float*)d_in[9];
    const float* pb1 = (const float*)d_in[10];
    const float* P2  = (const float*)d_in[11];
    const float* pb2 = (const float*)d_in[12];
    const float* P3  = (const float*)d_in[13];
    const float* pb3 = (const float*)d_in[14];
    float* out = (float*)d_out;

    char* ws = (char*)d_ws;
    int* cnt  = (int*)(ws + O_CNT);
    int* off  = (int*)(ws + O_OFF);
    int* cur  = (int*)(ws + O_CUR);
    int* bsum = (int*)(ws + O_BS);
    int* srcs = (int*)(ws + O_SRC);
    float* A  = (float*)(ws + O_A);
    float* B  = (float*)(ws + O_B);
    f16*   wt = (f16*)(ws + O_WT);

    const int* esrc = adj;
    const int* edst = adj + N_EDGES;

    const int SBLK = (N_NODES + 255) / 256;   // 196

    // W prep (tiny, independent)
    k_wprep<<<128, 256, 0, stream>>>(P1, P2, wt);

    // CSR build (dst-sorted src list), reused by all 3 layers
    hipMemsetAsync(cnt, 0, N_NODES * sizeof(int), stream);
    k_count<<<N_EDGES / 256, 256, 0, stream>>>(edst, cnt);
    k_scan1<<<SBLK, 256, 0, stream>>>(cnt, off, bsum);
    k_scan2<<<1, 256, 0, stream>>>(bsum, SBLK);
    k_scan3<<<SBLK, 256, 0, stream>>>(off, bsum, cur);
    k_scatter<<<N_EDGES / 256, 256, 0, stream>>>(esrc, edst, cur, srcs);

    const int gN = (N_NODES + 63) / 64;   // 782

    // GCN trunk (all fp32)
    k_gemm<<<gN, 512, 0, stream>>>(x, W1, A, N_NODES);
    k_agg<true><<<N_NODES / 2, 256, 0, stream>>>(A, off, srcs, b1, B);
    k_gemm<<<gN, 512, 0, stream>>>(B, W2, B, N_NODES);
    k_agg<true><<<N_NODES / 2, 256, 0, stream>>>(B, off, srcs, b2, A);
    k_gemm<<<gN, 512, 0, stream>>>(A, W3, A, N_NODES);
    k_agg<false><<<N_NODES / 2, 256, 0, stream>>>(A, off, srcs, b3, B); // B = emb

    // fused link predictor (MFMA fp16x2-split v2, 128 edges/block)
    const int gP = (N_QE + 127) / 128;    // 782
    k_pred<<<gP, 512, 0, stream>>>(B, te, wt, pb1, pb2, P3, pb3, out);
}

// Round 13
// 534.955 us; speedup vs baseline: 1.0866x; 1.0866x over previous
//
#include <hip/hip_runtime.h>
#include <math.h>

#define N_NODES 50000
#define N_EDGES 800000
#define N_QE    100000
#define D       128

// ---- workspace layout (bytes) ----
static const size_t O_CNT = 0;                        // int[N]
static const size_t O_OFF = 256u * 1024;              // int[N+1]
static const size_t O_CUR = 512u * 1024;              // int[N]
static const size_t O_BS  = 768u * 1024;              // int[256] block sums
static const size_t O_SRC = 1024u * 1024;             // int[E] (3.2 MB)
static const size_t O_A   = 8u << 20;                 // float[N*D] 25.6 MB
static const size_t O_B   = O_A + 25600000u;          // float[N*D] 25.6 MB

// ---- CSR build ----
__global__ void k_count(const int* __restrict__ dst, int* __restrict__ cnt) {
    int e = blockIdx.x * 256 + threadIdx.x;
    if (e < N_EDGES) atomicAdd(&cnt[dst[e]], 1);
}

__global__ __launch_bounds__(256)
void k_scan1(const int* __restrict__ cnt, int* __restrict__ off,
             int* __restrict__ bsum) {
    __shared__ int sh[256];
    const int t = threadIdx.x;
    const int i = blockIdx.x * 256 + t;
    int v = (i < N_NODES) ? cnt[i] : 0;
    sh[t] = v;
    __syncthreads();
    #pragma unroll
    for (int o = 1; o < 256; o <<= 1) {
        int u = (t >= o) ? sh[t - o] : 0;
        __syncthreads();
        sh[t] += u;
        __syncthreads();
    }
    if (i < N_NODES) off[i] = sh[t] - v;
    if (t == 255) bsum[blockIdx.x] = sh[255];
}

__global__ __launch_bounds__(256)
void k_scan2(int* __restrict__ bsum, int nblk) {
    __shared__ int sh[256];
    const int t = threadIdx.x;
    int v = (t < nblk) ? bsum[t] : 0;
    sh[t] = v;
    __syncthreads();
    #pragma unroll
    for (int o = 1; o < 256; o <<= 1) {
        int u = (t >= o) ? sh[t - o] : 0;
        __syncthreads();
        sh[t] += u;
        __syncthreads();
    }
    if (t < nblk) bsum[t] = sh[t] - v;
}

__global__ __launch_bounds__(256)
void k_scan3(int* __restrict__ off, const int* __restrict__ bsum,
             int* __restrict__ cur) {
    const int i = blockIdx.x * 256 + threadIdx.x;
    if (i < N_NODES) {
        int o = off[i] + bsum[blockIdx.x];
        off[i] = o;
        cur[i] = o;
    }
    if (i == 0) off[N_NODES] = N_EDGES;
}

__global__ void k_scatter(const int* __restrict__ src, const int* __restrict__ dst,
                          int* __restrict__ cur, int* __restrict__ srcs) {
    int e = blockIdx.x * 256 + threadIdx.x;
    if (e < N_EDGES) {
        int p = atomicAdd(&cur[dst[e]], 1);
        srcs[p] = src[e];
    }
}

// ---- GEMM: Y[rows x 128] = X[rows x 128] @ W[128 x 128], fp32 ----
// 512 threads / 64-row tile, 32-k chunks. In-place safe (X==Y).
__global__ __launch_bounds__(512)
void k_gemm(const float* __restrict__ X, const float* __restrict__ W,
            float* __restrict__ Y, int rows)
{
    __shared__ float xs[64][36];
    __shared__ float ws[32 * 128];
    const int tid = threadIdx.x;
    const int tx = tid & 31;
    const int ty = tid >> 5;
    const int row0 = blockIdx.x * 64;
    float acc[4][4] = {};

    for (int kc = 0; kc < 4; ++kc) {
        const int kb = kc * 32;
        __syncthreads();
        {
            int r = tid >> 3, kq = tid & 7;
            int gr = row0 + r; if (gr >= rows) gr = rows - 1;
            float4 v = *(const float4*)(X + (size_t)gr * D + kb + kq * 4);
            *(float4*)&xs[r][kq * 4] = v;
        }
        #pragma unroll
        for (int it = 0; it < 2; ++it) {
            int f = it * 512 + tid;
            int k = f >> 5, cq = f & 31;
            *(float4*)&ws[k * 128 + cq * 4] =
                *(const float4*)(W + (size_t)(kb + k) * D + cq * 4);
        }
        __syncthreads();

        #pragma unroll 2
        for (int k4 = 0; k4 < 32; k4 += 4) {
            float4 wv[4];
            #pragma unroll
            for (int kk = 0; kk < 4; ++kk)
                wv[kk] = *(const float4*)&ws[(k4 + kk) * 128 + tx * 4];
            #pragma unroll
            for (int i = 0; i < 4; ++i) {
                float4 xv = *(const float4*)&xs[ty * 4 + i][k4];
                float xk[4] = {xv.x, xv.y, xv.z, xv.w};
                #pragma unroll
                for (int kk = 0; kk < 4; ++kk) {
                    acc[i][0] = fmaf(xk[kk], wv[kk].x, acc[i][0]);
                    acc[i][1] = fmaf(xk[kk], wv[kk].y, acc[i][1]);
                    acc[i][2] = fmaf(xk[kk], wv[kk].z, acc[i][2]);
                    acc[i][3] = fmaf(xk[kk], wv[kk].w, acc[i][3]);
                }
            }
        }
    }

    #pragma unroll
    for (int i = 0; i < 4; ++i) {
        int gr = row0 + ty * 4 + i;
        if (gr < rows)
            *(float4*)(Y + (size_t)gr * D + tx * 4) =
                make_float4(acc[i][0], acc[i][1], acc[i][2], acc[i][3]);
    }
}

// ---- CSR aggregation (fp32): one node per HALF-WAVE ----
// Lanes 0-31 own node A, lanes 32-63 own node B: each 1-KB wave memory
// instruction serves 2 independent per-node streams -> 2x outstanding loads
// per wave vs the same-node-both-halves design. No shfl reduce, no LDS,
// no barrier. Sequential per-node summation (j ascending).
template<bool RELU>
__global__ __launch_bounds__(256)
void k_agg(const float* __restrict__ Hin, const int* __restrict__ off,
           const int* __restrict__ srcs, const float* __restrict__ bias,
           float* __restrict__ Hout)
{
    const int tid  = threadIdx.x;
    const int lane = tid & 63;
    const int half = lane >> 5;
    const int q    = lane & 31;
    const int wv   = tid >> 6;                       // 0..3
    const int n    = blockIdx.x * 8 + wv * 2 + half; // node per half-wave
    const int j0 = off[n], j1 = off[n + 1];

    float4 acc = make_float4(0.f, 0.f, 0.f, 0.f);
    int j = j0;
    while (j < j1) {
        int cnt = j1 - j; if (cnt > 32) cnt = 32;
        int idx = (q < cnt) ? srcs[j + q] : 0;       // this half's next 32 src ids
        #pragma unroll 8
        for (int k = 0; k < cnt; ++k) {
            int s = __shfl(idx, half * 32 + k, 64);  // sources stay in own half
            const float4 v = *(const float4*)(Hin + (size_t)s * D + q * 4);
            acc.x += v.x; acc.y += v.y; acc.z += v.z; acc.w += v.w;
        }
        j += cnt;
    }
    const float4 bb = *(const float4*)(bias + q * 4);
    float4 o = make_float4(acc.x + bb.x, acc.y + bb.y,
                           acc.z + bb.z, acc.w + bb.w);
    if (RELU) {
        o.x = fmaxf(o.x, 0.f); o.y = fmaxf(o.y, 0.f);
        o.z = fmaxf(o.z, 0.f); o.w = fmaxf(o.w, 0.f);
    }
    *(float4*)(Hout + (size_t)n * D + q * 4) = o;
}

// ---- fused link predictor, 512 threads / 64 edges per block (R8 scalar) ----
__global__ __launch_bounds__(512)
void k_pred(const float* __restrict__ emb, const int* __restrict__ te,
            const float* __restrict__ P1, const float* __restrict__ pb1,
            const float* __restrict__ P2, const float* __restrict__ pb2,
            const float* __restrict__ P3, const float* __restrict__ pb3,
            float* __restrict__ out)
{
    __shared__ float xs[64][132];     // full 128-k activations, +4 pad
    __shared__ float ws[64 * 128];    // one 64-k weight chunk
    const int tid = threadIdx.x;      // 0..511
    const int tx = tid & 31;          // cols tx*4 .. +3
    const int ty = tid >> 5;          // 0..15, rows ty*4 .. +3
    const int row0 = blockIdx.x * 64;

    // stage z0 = emb[s] * emb[d]
    #pragma unroll
    for (int it = 0; it < 4; ++it) {
        int slot = it * 512 + tid;          // 0..2047
        int r = slot >> 5, c4 = slot & 31;
        int e = row0 + r; if (e >= N_QE) e = N_QE - 1;
        int s = te[e * 2], d = te[e * 2 + 1];
        float4 a = *(const float4*)(emb + (size_t)s * D + c4 * 4);
        float4 b = *(const float4*)(emb + (size_t)d * D + c4 * 4);
        *(float4*)&xs[r][c4 * 4] =
            make_float4(a.x * b.x, a.y * b.y, a.z * b.z, a.w * b.w);
    }

    float acc[4][4];

    #pragma unroll
    for (int layer = 0; layer < 2; ++layer) {
        const float* W = layer ? P2 : P1;
        const float* bb = layer ? pb2 : pb1;
        #pragma unroll
        for (int i = 0; i < 4; ++i)
            #pragma unroll
            for (int c = 0; c < 4; ++c) acc[i][c] = 0.f;

        for (int kc = 0; kc < 2; ++kc) {
            const int kb = kc * 64;
            __syncthreads();
            #pragma unroll
            for (int it = 0; it < 4; ++it) {
                int f = it * 512 + tid;   // 0..2047
                int k = f >> 5, cq = f & 31;
                *(float4*)&ws[k * 128 + cq * 4] =
                    *(const float4*)(W + (size_t)(kb + k) * D + cq * 4);
            }
            __syncthreads();

            #pragma unroll 2
            for (int k4 = 0; k4 < 64; k4 += 4) {
                float4 wv[4];
                #pragma unroll
                for (int kk = 0; kk < 4; ++kk)
                    wv[kk] = *(const float4*)&ws[(k4 + kk) * 128 + tx * 4];
                #pragma unroll
                for (int i = 0; i < 4; ++i) {
                    float4 xv = *(const float4*)&xs[ty * 4 + i][kb + k4];
                    float xk[4] = {xv.x, xv.y, xv.z, xv.w};
                    #pragma unroll
                    for (int kk = 0; kk < 4; ++kk) {
                        acc[i][0] = fmaf(xk[kk], wv[kk].x, acc[i][0]);
                        acc[i][1] = fmaf(xk[kk], wv[kk].y, acc[i][1]);
                        acc[i][2] = fmaf(xk[kk], wv[kk].z, acc[i][2]);
                        acc[i][3] = fmaf(xk[kk], wv[kk].w, acc[i][3]);
                    }
                }
            }
        }
        // bias + relu
        #pragma unroll
        for (int i = 0; i < 4; ++i) {
            acc[i][0] = fmaxf(acc[i][0] + bb[tx * 4 + 0], 0.f);
            acc[i][1] = fmaxf(acc[i][1] + bb[tx * 4 + 1], 0.f);
            acc[i][2] = fmaxf(acc[i][2] + bb[tx * 4 + 2], 0.f);
            acc[i][3] = fmaxf(acc[i][3] + bb[tx * 4 + 3], 0.f);
        }
        if (layer == 0) {
            __syncthreads();
            #pragma unroll
            for (int i = 0; i < 4; ++i)
                *(float4*)&xs[ty * 4 + i][tx * 4] =
                    make_float4(acc[i][0], acc[i][1], acc[i][2], acc[i][3]);
        }
    }

    // epilogue: v = z @ P3 + pb3 (2 cols), reduce over the 32 tx lanes
    float4 p3a = *(const float4*)(P3 + tx * 8);
    float4 p3b = *(const float4*)(P3 + tx * 8 + 4);
    const float q0 = pb3[0], q1 = pb3[1];
    #pragma unroll
    for (int i = 0; i < 4; ++i) {
        float p0 = acc[i][0] * p3a.x + acc[i][1] * p3a.z
                 + acc[i][2] * p3b.x + acc[i][3] * p3b.z;
        float p1 = acc[i][0] * p3a.y + acc[i][1] * p3a.w
                 + acc[i][2] * p3b.y + acc[i][3] * p3b.w;
        #pragma unroll
        for (int o = 1; o < 32; o <<= 1) {
            p0 += __shfl_xor(p0, o, 64);
            p1 += __shfl_xor(p1, o, 64);
        }
        if (tx == 0) {
            int gr = row0 + ty * 4 + i;
            if (gr < N_QE) {
                float v0 = p0 + q0, v1 = p1 + q1;
                float nrm = fmaxf(sqrtf(v0 * v0 + v1 * v1), 1e-12f);
                v0 /= nrm; v1 /= nrm;
                float m = fmaxf(v0, v1);
                float lse = m + logf(expf(v0 - m) + expf(v1 - m));
                out[gr * 2]     = v0 - lse;
                out[gr * 2 + 1] = v1 - lse;
            }
        }
    }
}

extern "C" void kernel_launch(void* const* d_in, const int* in_sizes, int n_in,
                              void* d_out, int out_size, void* d_ws, size_t ws_size,
                              hipStream_t stream)
{
    (void)in_sizes; (void)n_in; (void)out_size; (void)ws_size;
    const float* x   = (const float*)d_in[0];
    const int*   adj = (const int*)d_in[1];
    const int*   te  = (const int*)d_in[2];
    const float* W1  = (const float*)d_in[3];
    const float* b1  = (const float*)d_in[4];
    const float* W2  = (const float*)d_in[5];
    const float* b2  = (const float*)d_in[6];
    const float* W3  = (const float*)d_in[7];
    const float* b3  = (const float*)d_in[8];
    const float* P1  = (const float*)d_in[9];
    const float* pb1 = (const float*)d_in[10];
    const float* P2  = (const float*)d_in[11];
    const float* pb2 = (const float*)d_in[12];
    const float* P3  = (const float*)d_in[13];
    const float* pb3 = (const float*)d_in[14];
    float* out = (float*)d_out;

    char* ws = (char*)d_ws;
    int* cnt  = (int*)(ws + O_CNT);
    int* off  = (int*)(ws + O_OFF);
    int* cur  = (int*)(ws + O_CUR);
    int* bsum = (int*)(ws + O_BS);
    int* srcs = (int*)(ws + O_SRC);
    float* A  = (float*)(ws + O_A);
    float* B  = (float*)(ws + O_B);

    const int* esrc = adj;
    const int* edst = adj + N_EDGES;

    const int SBLK = (N_NODES + 255) / 256;   // 196

    // CSR build (dst-sorted src list), reused by all 3 layers
    hipMemsetAsync(cnt, 0, N_NODES * sizeof(int), stream);
    k_count<<<N_EDGES / 256, 256, 0, stream>>>(edst, cnt);
    k_scan1<<<SBLK, 256, 0, stream>>>(cnt, off, bsum);
    k_scan2<<<1, 256, 0, stream>>>(bsum, SBLK);
    k_scan3<<<SBLK, 256, 0, stream>>>(off, bsum, cur);
    k_scatter<<<N_EDGES / 256, 256, 0, stream>>>(esrc, edst, cur, srcs);

    const int gN = (N_NODES + 63) / 64;   // 782
    const int gQ = (N_QE + 63) / 64;      // 1563

    // GCN trunk (all fp32)
    k_gemm<<<gN, 512, 0, stream>>>(x, W1, A, N_NODES);
    k_agg<true><<<N_NODES / 8, 256, 0, stream>>>(A, off, srcs, b1, B);
    k_gemm<<<gN, 512, 0, stream>>>(B, W2, B, N_NODES);
    k_agg<true><<<N_NODES / 8, 256, 0, stream>>>(B, off, srcs, b2, A);
    k_gemm<<<gN, 512, 0, stream>>>(A, W3, A, N_NODES);
    k_agg<false><<<N_NODES / 8, 256, 0, stream>>>(A, off, srcs, b3, B); // B = emb

    // fused link predictor (512 threads / 64 edges per block)
    k_pred<<<gQ, 512, 0, stream>>>(B, te, P1, pb1, P2, pb2, P3, pb3, out);
}